// Round 17
// baseline (833.528 us; speedup 1.0000x reference)
//
#include <hip/hip_runtime.h>
#include <hip/hip_bf16.h>

#define LQ 2048
#define LKV 2048
#define DM 512
#define NH 8
#define DK 64

typedef __attribute__((ext_vector_type(8))) __bf16 bf16x8;
typedef __attribute__((ext_vector_type(4))) float f32x4;
typedef __attribute__((ext_vector_type(16))) float f32x16;

#define AS1 __attribute__((address_space(1)))
#define AS3 __attribute__((address_space(3)))

static __device__ __forceinline__ unsigned short f2bf(float x) {
  unsigned u = __float_as_uint(x);
  return (unsigned short)((u + 0x7fffu + ((u >> 16) & 1u)) >> 16);
}
static __device__ __forceinline__ float bf2f(unsigned short u) {
  return __uint_as_float(((unsigned)u) << 16);
}
static __device__ __forceinline__ bf16x8 cvt8(f32x4 a, f32x4 b) {
  bf16x8 r;
  r[0] = (__bf16)a[0]; r[1] = (__bf16)a[1]; r[2] = (__bf16)a[2]; r[3] = (__bf16)a[3];
  r[4] = (__bf16)b[0]; r[5] = (__bf16)b[1]; r[6] = (__bf16)b[2]; r[7] = (__bf16)b[3];
  return r;
}

// ---------------------------------------------------------------------------
// Transpose+convert W[512][512] f32 -> Wt bf16 (Wt[n][k] = W[k][n]).
// Blocks (z==0, y==0) additionally emit wbf[b][l] = bf16(w[l]) in the
// phi-permuted order (swap bits 2,3 of l&15) used by attn's w fragments.
// ---------------------------------------------------------------------------
__global__ __launch_bounds__(256) void transpose_w(
    const float* __restrict__ Wq, const float* __restrict__ Wk,
    const float* __restrict__ Wv, const float* __restrict__ Wo,
    const float* __restrict__ wts,
    unsigned short* __restrict__ WtAll, unsigned short* __restrict__ wbf)
{
  const float* W = blockIdx.z == 0 ? Wq : blockIdx.z == 1 ? Wk : blockIdx.z == 2 ? Wv : Wo;
  unsigned short* Wt = WtAll + (size_t)blockIdx.z * DM * DM;
  __shared__ float tile[32][33];
  const int t = threadIdx.x;
  if (blockIdx.z == 0 && blockIdx.y == 0) {
    int idx = blockIdx.x * 512 + t * 2;    // 16 blocks x 512 = 8192 = B*LKV
#pragma unroll
    for (int i = 0; i < 2; ++i) {
      int kv = idx + i;
      int r = kv & 15;
      int ph = (r & 3) | ((r & 4) << 1) | ((r & 8) >> 1);   // swap bits 2,3
      wbf[(kv & ~15) | ph] = f2bf(wts[kv]);
    }
  }
  const int tr = t >> 3;
  const int tc4 = (t & 7) * 4;
  const int k0 = blockIdx.x * 32, n0 = blockIdx.y * 32;
  float4 v = *(const float4*)(W + (size_t)(k0 + tr) * DM + n0 + tc4);
  tile[tr][tc4 + 0] = v.x; tile[tr][tc4 + 1] = v.y;
  tile[tr][tc4 + 2] = v.z; tile[tr][tc4 + 3] = v.w;
  __syncthreads();
  ushort4 o;
  o.x = f2bf(tile[tc4 + 0][tr]);
  o.y = f2bf(tile[tc4 + 1][tr]);
  o.z = f2bf(tile[tc4 + 2][tr]);
  o.w = f2bf(tile[tc4 + 3][tr]);
  *(ushort4*)(Wt + (size_t)(n0 + tr) * DM + k0 + tc4) = o;
}

// ---------------------------------------------------------------------------
// QKV projection GEMM with counted-vmcnt double-buffered pipeline.
// A f32 via global_load_lds (XOR-swizzled source); bf16 convert after LDS
// read. B via global_load_lds ((row>>1)&3 slot swizzle). XCD-bijective grid
// 768 = 3 modes x 64 m x 4 n, block 256. LDS 48 KB dbuf.
// Outputs ALL row-major head-major [B,H,L,64]: Q scaled by log2e/8, K, V.
// ---------------------------------------------------------------------------
__global__ __launch_bounds__(256) void gemm_qkv(
    const float* __restrict__ qin, const float* __restrict__ kin, const float* __restrict__ vin,
    const unsigned short* __restrict__ WtAll,
    const float* __restrict__ bq, const float* __restrict__ bk, const float* __restrict__ bv,
    unsigned short* __restrict__ qh, unsigned short* __restrict__ kh, unsigned short* __restrict__ vh)
{
  const int bid = blockIdx.x;
  const int x = bid & 7, j = bid >> 3;
  const int p = x + 8 * (j >> 2);
  const int nt = j & 3;
  const int mode = p >> 6, mtile = p & 63;

  const float* A = mode == 0 ? qin : (mode == 1 ? kin : vin);
  const unsigned short* Bt = WtAll + (size_t)mode * DM * DM;
  const float* bias = mode == 0 ? bq : (mode == 1 ? bk : bv);
  unsigned short* out = mode == 0 ? qh : (mode == 1 ? kh : vh);
  const float scale = (mode == 0) ? 0.18033688011112042f : 1.0f; // log2(e)/8

  // [buf2][As 16KB | Bs 8KB]
  __shared__ __align__(16) char sm[49152];

  const int tid = threadIdx.x;
  const int lane = tid & 63;
  const int w = tid >> 6;
  const int wr = w >> 1, wc = w & 1;
  const int l15 = lane & 15, g = lane >> 4;
  const int m0 = mtile * 128, n0 = nt * 128;

#define STAGEQ(buf, t)                                                                    \
  do {                                                                                    \
    int k0_ = (t) * 32;                                                                   \
    char* As_ = sm + (buf) * 24576;                                                       \
    char* Bs_ = As_ + 16384;                                                              \
    _Pragma("unroll")                                                                     \
    for (int i = 0; i < 4; ++i) {                                                         \
      int c = tid + i * 256;                                                              \
      int row = c >> 3, slot = c & 7;                                                     \
      const float* src = A + (size_t)(m0 + row) * DM + k0_ + ((slot ^ (row & 7)) << 2);   \
      __builtin_amdgcn_global_load_lds((const AS1 unsigned*)src,                          \
                                       (AS3 unsigned*)(As_ + c * 16), 16, 0, 0);          \
    }                                                                                     \
    _Pragma("unroll")                                                                     \
    for (int i = 0; i < 2; ++i) {                                                         \
      int c = tid + i * 256;                                                              \
      int row = c >> 2, slot = c & 3;                                                     \
      const unsigned short* src = Bt + (size_t)(n0 + row) * DM + k0_ + ((slot ^ ((row >> 1) & 3)) * 8); \
      __builtin_amdgcn_global_load_lds((const AS1 unsigned*)src,                          \
                                       (AS3 unsigned*)(Bs_ + c * 16), 16, 0, 0);          \
    }                                                                                     \
  } while (0)

  f32x4 acc[4][4] = {};
  STAGEQ(0, 0);
  int cur = 0;

  for (int t = 0; t < 16; ++t) {
    if (t < 15) {
      STAGEQ(cur ^ 1, t + 1);
      asm volatile("s_waitcnt vmcnt(6)" ::: "memory");   // stage t landed; 6 newest in flight
    } else {
      asm volatile("s_waitcnt vmcnt(0)" ::: "memory");
    }
    __builtin_amdgcn_s_barrier();      // A: buf cur complete

    const char* As_ = sm + cur * 24576;
    const char* Bs_ = As_ + 16384;

    __builtin_amdgcn_s_setprio(1);
    bf16x8 af[4], bfr[4];
#pragma unroll
    for (int mi = 0; mi < 4; ++mi) {
      int row = wr * 64 + mi * 16 + l15;
      f32x4 a0 = *(const f32x4*)(As_ + row * 128 + (((2 * g) ^ (row & 7)) << 4));
      f32x4 a1 = *(const f32x4*)(As_ + row * 128 + (((2 * g + 1) ^ (row & 7)) << 4));
      af[mi] = cvt8(a0, a1);
    }
#pragma unroll
    for (int ni = 0; ni < 4; ++ni) {
      int row = wc * 64 + ni * 16 + l15;
      bfr[ni] = *(const bf16x8*)(Bs_ + row * 64 + ((g ^ ((row >> 1) & 3)) * 16));
    }
#pragma unroll
    for (int mi = 0; mi < 4; ++mi)
#pragma unroll
      for (int ni = 0; ni < 4; ++ni)
        acc[mi][ni] = __builtin_amdgcn_mfma_f32_16x16x32_bf16(af[mi], bfr[ni], acc[mi][ni], 0, 0, 0);
    __builtin_amdgcn_s_setprio(0);

    asm volatile("s_waitcnt lgkmcnt(0)" ::: "memory");
    __builtin_amdgcn_s_barrier();      // B: reads of buf cur done; overwrite safe
    cur ^= 1;
  }
#undef STAGEQ

#pragma unroll
  for (int mi = 0; mi < 4; ++mi) {
#pragma unroll
    for (int ni = 0; ni < 4; ++ni) {
      int n = n0 + wc * 64 + ni * 16 + l15;
      float bs = bias[n];
      int h = n >> 6, d = n & 63;
#pragma unroll
      for (int r = 0; r < 4; ++r) {
        int m = m0 + wr * 64 + mi * 16 + g * 4 + r;
        int b = m >> 11, li = m & 2047;
        float val = (acc[mi][ni][r] + bs) * scale;
        out[(((size_t)(b * NH + h)) * LQ + li) * DK + d] = f2bf(val);
      }
    }
  }
}

// ---------------------------------------------------------------------------
// Output GEMM with counted-vmcnt double-buffered pipeline (vmcnt(4)) and
// XCD-bijective grid: all 4 n-tiles of one m-panel land on one XCD.
// grid 256 (1D), block 256. A bf16 @ Wo^T + bo -> f32.
// ---------------------------------------------------------------------------
__global__ __launch_bounds__(256) void gemm_out(
    const unsigned short* __restrict__ A, const unsigned short* __restrict__ Bt,
    const float* __restrict__ bias, float* __restrict__ out)
{
  // [buf2][Al 8KB | Bl 8KB]
  __shared__ __align__(16) char sm[32768];
  const int bid = blockIdx.x;
  const int x = bid & 7, j = bid >> 3;
  const int p = x + 8 * (j >> 2);        // m-tile 0..63 -> XCD p&7
  const int nt = j & 3;
  const int tid = threadIdx.x;
  const int lane = tid & 63;
  const int w = tid >> 6;
  const int wr = w >> 1, wc = w & 1;
  const int l15 = lane & 15, g = lane >> 4;
  const int m0 = p * 128, n0 = nt * 128;

#define STAGEO(buf, t)                                                                    \
  do {                                                                                    \
    int k0_ = (t) * 32;                                                                   \
    char* Al_ = sm + (buf) * 16384;                                                       \
    char* Bl_ = Al_ + 8192;                                                               \
    _Pragma("unroll")                                                                     \
    for (int i = 0; i < 2; ++i) {                                                         \
      int c = tid + i * 256;                                                              \
      int row = c >> 2, slot = c & 3;                                                     \
      int so = (slot ^ ((row >> 1) & 3)) * 8;                                             \
      __builtin_amdgcn_global_load_lds(                                                   \
          (const AS1 unsigned*)(A + (size_t)(m0 + row) * DM + k0_ + so),                  \
          (AS3 unsigned*)(Al_ + c * 16), 16, 0, 0);                                       \
      __builtin_amdgcn_global_load_lds(                                                   \
          (const AS1 unsigned*)(Bt + (size_t)(n0 + row) * DM + k0_ + so),                 \
          (AS3 unsigned*)(Bl_ + c * 16), 16, 0, 0);                                       \
    }                                                                                     \
  } while (0)

  f32x4 acc[4][4] = {};
  STAGEO(0, 0);
  int cur = 0;

  for (int t = 0; t < 16; ++t) {
    if (t < 15) {
      STAGEO(cur ^ 1, t + 1);
      asm volatile("s_waitcnt vmcnt(4)" ::: "memory");
    } else {
      asm volatile("s_waitcnt vmcnt(0)" ::: "memory");
    }
    __builtin_amdgcn_s_barrier();

    const char* Al_ = sm + cur * 16384;
    const char* Bl_ = Al_ + 8192;

    __builtin_amdgcn_s_setprio(1);
    bf16x8 af[4], bfr[4];
#pragma unroll
    for (int mi = 0; mi < 4; ++mi) {
      int row = wr * 64 + mi * 16 + l15;
      af[mi] = *(const bf16x8*)(Al_ + row * 64 + ((g ^ ((row >> 1) & 3)) * 16));
    }
#pragma unroll
    for (int ni = 0; ni < 4; ++ni) {
      int row = wc * 64 + ni * 16 + l15;
      bfr[ni] = *(const bf16x8*)(Bl_ + row * 64 + ((g ^ ((row >> 1) & 3)) * 16));
    }
#pragma unroll
    for (int mi = 0; mi < 4; ++mi)
#pragma unroll
      for (int ni = 0; ni < 4; ++ni)
        acc[mi][ni] = __builtin_amdgcn_mfma_f32_16x16x32_bf16(af[mi], bfr[ni], acc[mi][ni], 0, 0, 0);
    __builtin_amdgcn_s_setprio(0);

    asm volatile("s_waitcnt lgkmcnt(0)" ::: "memory");
    __builtin_amdgcn_s_barrier();
    cur ^= 1;
  }
#undef STAGEO

#pragma unroll
  for (int mi = 0; mi < 4; ++mi) {
#pragma unroll
    for (int ni = 0; ni < 4; ++ni) {
      int n = n0 + wc * 64 + ni * 16 + l15;
      float bs = bias[n];
#pragma unroll
      for (int r = 0; r < 4; ++r) {
        int m = m0 + wr * 64 + mi * 16 + g * 4 + r;
        out[(size_t)m * DM + n] = acc[mi][ni][r] + bs;
      }
    }
  }
}

// ---------------------------------------------------------------------------
// prep_v: V row-major -> w-folded B-fragment layout with kv-PERMUTED k-order
// (phi: swap bits 2<->3 of kv&15). grid (32, 32), block 256.
// ---------------------------------------------------------------------------
__global__ __launch_bounds__(256) void prep_v(
    const unsigned short* __restrict__ vh, const float* __restrict__ wts,
    unsigned short* __restrict__ vf)
{
  __shared__ __align__(16) unsigned short t[64 * 72];
  const int bh = blockIdx.y, l0 = blockIdx.x * 64;
  const int b = bh >> 3;
  const size_t base = (size_t)bh * LKV * DK;
  const int tid = threadIdx.x;

#pragma unroll
  for (int i = 0; i < 2; ++i) {
    int idx = tid + i * 256;
    int row = idx >> 3, seg = idx & 7;
    *(int4*)(&t[row * 72 + seg * 8]) =
        *(const int4*)(vh + base + (size_t)(l0 + row) * DK + seg * 8);
  }
  __syncthreads();
#pragma unroll
  for (int i = 0; i < 2; ++i) {
    int idx = tid + i * 256;
    int d = idx >> 3, seg = idx & 7;
    int kvg = l0 + seg * 8;
    float4 wa = *(const float4*)(wts + b * LKV + kvg);
    float4 wb4 = *(const float4*)(wts + b * LKV + kvg + 4);
    unsigned short r0 = f2bf(wa.x * bf2f(t[(seg * 8 + 0) * 72 + d]));
    unsigned short r1 = f2bf(wa.y * bf2f(t[(seg * 8 + 1) * 72 + d]));
    unsigned short r2 = f2bf(wa.z * bf2f(t[(seg * 8 + 2) * 72 + d]));
    unsigned short r3 = f2bf(wa.w * bf2f(t[(seg * 8 + 3) * 72 + d]));
    unsigned short r4 = f2bf(wb4.x * bf2f(t[(seg * 8 + 4) * 72 + d]));
    unsigned short r5 = f2bf(wb4.y * bf2f(t[(seg * 8 + 5) * 72 + d]));
    unsigned short r6 = f2bf(wb4.z * bf2f(t[(seg * 8 + 6) * 72 + d]));
    unsigned short r7 = f2bf(wb4.w * bf2f(t[(seg * 8 + 7) * 72 + d]));
    int T = kvg >> 4, s = (kvg >> 3) & 1, dh = d >> 5, dl = d & 31;
    size_t slot = (((size_t)bh * 128 + T) * 2 + dh) * 64;
    ushort4 lo4, hi4;
    lo4.x = r0; lo4.y = r1; lo4.z = r2; lo4.w = r3;
    hi4.x = r4; hi4.y = r5; hi4.z = r6; hi4.w = r7;
    *(ushort4*)(vf + (slot + dl) * 8 + 4 * s) = lo4;
    *(ushort4*)(vf + (slot + dl + 32) * 8 + 4 * s) = hi4;
  }
}

// ---------------------------------------------------------------------------
// Flash attention v6: OCCUPANCY DOUBLING. 1024-thread blocks = 16 waves =
// 4 wq x 4 kvq (kv-split x4) -> 2 blocks/CU x 16 waves = 32 waves/CU
// (8/SIMD, HW max) vs r14's 16. Per-wave body is verbatim r14 (16 iters of
// 32 kv). K/V tiles stay 4-way wq-shared (LDS 64 KB dbuf + 4 KB w). 4-way
// partial combine via 3-barrier staged reduction through two aliased LDS
// buffers (L packed into f32 column 64). VGPR <= 64 (launch_bounds(1024,8)).
// grid 512 = 32 bh (XCD-grouped) x 16 qb.
// ---------------------------------------------------------------------------
__global__ __launch_bounds__(1024, 8) void attn_fwd(
    const unsigned short* __restrict__ qh, const unsigned short* __restrict__ kh,
    const unsigned short* __restrict__ vf, const unsigned short* __restrict__ wbf,
    unsigned short* __restrict__ ao)
{
  const int bid = blockIdx.x;
  const int xcd = bid & 7, wi = bid >> 3;   // 512 blocks, 64 per XCD
  const int bh = xcd * 4 + (wi >> 4);       // 4 bh per XCD (L2 locality)
  const int qb = wi & 15;
  const int b = bh >> 3, h = bh & 7;
  const int tid = threadIdx.x, lane = tid & 63, w = tid >> 6;  // 16 waves
  const int wq = w & 3, kvq = w >> 2;
  const int l31 = lane & 31, hi = lane >> 5;

  // [0,65536) K/V dbuf: [buf2][kvq4][K 4KB | V 4KB] | [65536,69632) w bf16 |
  // [69632,69696) zeros. Post-loop alias: OA [128][68] f32 @0, OB @34816.
  __shared__ __align__(16) char smem[69696];

  const size_t kv_bh = (size_t)bh * (LKV * DK);
  const unsigned short* khb = kh + kv_bh;
  const unsigned short* vfb = vf + kv_bh;

  const int q0 = qb * 128 + wq * 32;

#define STAGE(buf, t)                                                                     \
  do {                                                                                    \
    int tg_ = kvq * 16 + (t);                                                             \
    int kv_ = tg_ * 32 + (lane & 31);                                                     \
    const unsigned short* ks_ = khb + (size_t)kv_ * DK + wq * 16 + (lane >> 5) * 8;       \
    const unsigned short* vs_ = vfb + ((size_t)(tg_ * 4 + wq) * 64 + lane) * 8;           \
    char* kd_ = smem + (buf) * 32768 + kvq * 8192 + wq * 1024;                            \
    char* vd_ = smem + (buf) * 32768 + kvq * 8192 + 4096 + wq * 1024;                     \
    __builtin_amdgcn_global_load_lds((const AS1 unsigned*)ks_, (AS3 unsigned*)kd_, 16, 0, 0); \
    __builtin_amdgcn_global_load_lds((const AS1 unsigned*)vs_, (AS3 unsigned*)vd_, 16, 0, 0); \
  } while (0)

  // ---- prologue: w -> LDS, zero pad, first kv tile -> LDS, Q -> regs ----
  if (tid < 256)
    __builtin_amdgcn_global_load_lds((const AS1 unsigned*)(wbf + b * LKV + tid * 8),
                                     (AS3 unsigned*)(smem + 65536 + tid * 16), 16, 0, 0);
  if (tid < 16) *(int*)(smem + 69632 + tid * 4) = 0;
  STAGE(0, 0);

  bf16x8 qf[4];
  {
    const unsigned short* qp = qh + kv_bh + (size_t)(q0 + l31) * DK + hi * 8;
#pragma unroll
    for (int cq = 0; cq < 4; ++cq) qf[cq] = *(const bf16x8*)(qp + cq * 16);
  }
  __syncthreads();

  const char* wl = smem + 65536 + kvq * 1024 + hi * 16;
  const char* zpad = smem + 69632;
  f32x16 accO0 = {}, accO1 = {}, accL = {};
  int cur = 0;

#pragma unroll 2
  for (int t = 0; t < 16; ++t) {
    if (t < 15) {
      STAGE(cur ^ 1, t + 1);
      asm volatile("s_waitcnt vmcnt(2)" ::: "memory");   // buf cur landed; 2 newest in flight
    } else {
      asm volatile("s_waitcnt vmcnt(0)" ::: "memory");
    }
    __builtin_amdgcn_s_barrier();      // A: buf cur complete for all waves

    const char* Kb = smem + cur * 32768 + kvq * 8192;
    const char* Vb = Kb + 4096;

    __builtin_amdgcn_s_setprio(1);
    // ---- S^T = K.Q^T ----
    f32x16 s = {};
#pragma unroll
    for (int cq = 0; cq < 4; ++cq) {
      bf16x8 kfr = *(const bf16x8*)(Kb + cq * 1024 + lane * 16);
      s = __builtin_amdgcn_mfma_f32_32x32x16_bf16(kfr, qf[cq], s, 0, 0, 0);
    }

    // ---- u = exp2(S), pack bf16 pairs; C-layout == PV A-layout (perm'd) ----
    union { unsigned u[8]; bf16x8 v[2]; } P;
#pragma unroll
    for (int r2 = 0; r2 < 8; ++r2) {
      float lo = __builtin_amdgcn_exp2f(s[2 * r2]);
      float hv = __builtin_amdgcn_exp2f(s[2 * r2 + 1]);
      __bf16 bl = (__bf16)lo, bh2 = (__bf16)hv;
      unsigned short ul = __builtin_bit_cast(unsigned short, bl);
      unsigned short uh = __builtin_bit_cast(unsigned short, bh2);
      P.u[r2] = (unsigned)ul | ((unsigned)uh << 16);
    }

    // w-fragment base: real w row for lanes l31==0, zero pad otherwise
    const char* wsel = (l31 == 0) ? (wl + t * 64) : zpad;

    // ---- PV + denominator, pa = P.v[c] directly ----
#pragma unroll
    for (int c = 0; c < 2; ++c) {
      bf16x8 vb0 = *(const bf16x8*)(Vb + (c * 2 + 0) * 1024 + lane * 16);
      bf16x8 vb1 = *(const bf16x8*)(Vb + (c * 2 + 1) * 1024 + lane * 16);
      bf16x8 wb = *(const bf16x8*)(wsel + c * 32);

      accO0 = __builtin_amdgcn_mfma_f32_32x32x16_bf16(P.v[c], vb0, accO0, 0, 0, 0);
      accO1 = __builtin_amdgcn_mfma_f32_32x32x16_bf16(P.v[c], vb1, accO1, 0, 0, 0);
      accL  = __builtin_amdgcn_mfma_f32_32x32x16_bf16(P.v[c], wb,  accL,  0, 0, 0);
    }
    __builtin_amdgcn_s_setprio(0);

    asm volatile("s_waitcnt lgkmcnt(0)" ::: "memory");
    __builtin_amdgcn_s_barrier();      // B: all reads of buf cur done
    cur ^= 1;
  }
#undef STAGE

  // ---- 4-way combine: staged reduction through OA/OB, L in column 64 ----
  float* OA = (float*)smem;              // [128][68]
  float* OB = (float*)(smem + 34816);    // [128][68]
  // phase 1: kvq1 -> OA, kvq3 -> OB
  if (kvq & 1) {
    float* Ox = (kvq == 1) ? OA : OB;
#pragma unroll
    for (int r = 0; r < 16; ++r) {
      int qp_ = (r & 3) + 8 * (r >> 2) + 4 * hi;
      int row = wq * 32 + qp_;
      Ox[row * 68 + l31] = accO0[r];
      Ox[row * 68 + 32 + l31] = accO1[r];
      if (l31 == 0) Ox[row * 68 + 64] = accL[r];
    }
  }
  __syncthreads();
  // phase 2: kvq0 += OA, kvq2 += OB (in registers)
  if ((kvq & 1) == 0) {
    const float* Ox = (kvq == 0) ? OA : OB;
#pragma unroll
    for (int r = 0; r < 16; ++r) {
      int qp_ = (r & 3) + 8 * (r >> 2) + 4 * hi;
      int row = wq * 32 + qp_;
      accO0[r] += Ox[row * 68 + l31];
      accO1[r] += Ox[row * 68 + 32 + l31];
      if (l31 == 0) accL[r] += Ox[row * 68 + 64];
    }
  }
  __syncthreads();
  // phase 2b: kvq2 writes its (2+3) sum to OA
  if (kvq == 2) {
#pragma unroll
    for (int r = 0; r < 16; ++r) {
      int qp_ = (r & 3) + 8 * (r >> 2) + 4 * hi;
      int row = wq * 32 + qp_;
      OA[row * 68 + l31] = accO0[r];
      OA[row * 68 + 32 + l31] = accO1[r];
      if (l31 == 0) OA[row * 68 + 64] = accL[r];
    }
  }
  __syncthreads();
  // phase 3: kvq0 finalizes
  if (kvq == 0) {
#pragma unroll
    for (int r = 0; r < 16; ++r) {
      int qp_ = (r & 3) + 8 * (r >> 2) + 4 * hi;
      int row = wq * 32 + qp_;
      float o0 = accO0[r] + OA[row * 68 + l31];
      float o1 = accO1[r] + OA[row * 68 + 32 + l31];
      float Lown = accL[r] + ((l31 == 0) ? OA[row * 68 + 64] : 0.0f);
      float L = __shfl(Lown, lane & 32);
      float inv = 1.0f / L;
      size_t off = ((size_t)(b * LQ + q0 + qp_)) * DM + h * DK;
      ao[off + l31] = f2bf(o0 * inv);
      ao[off + 32 + l31] = f2bf(o1 * inv);
    }
  }
}

// ---------------------------------------------------------------------------
extern "C" void kernel_launch(void* const* d_in, const int* in_sizes, int n_in,
                              void* d_out, int out_size, void* d_ws, size_t ws_size,
                              hipStream_t stream)
{
  const float* q  = (const float*)d_in[0];
  const float* k  = (const float*)d_in[1];
  const float* v  = (const float*)d_in[2];
  const float* wt = (const float*)d_in[3];
  const float* Wq = (const float*)d_in[4];
  const float* bq = (const float*)d_in[5];
  const float* Wk = (const float*)d_in[6];
  const float* bk = (const float*)d_in[7];
  const float* Wv = (const float*)d_in[8];
  const float* bv = (const float*)d_in[9];
  const float* Wo = (const float*)d_in[10];
  const float* bo = (const float*)d_in[11];

  char* ws = (char*)d_ws;
  unsigned short* qh = (unsigned short*)(ws + 0);           //  8 MiB  [B,H,L,64] (scaled)
  unsigned short* kh = (unsigned short*)(ws + 8388608);     //  8 MiB  [B,H,L,64] row-major K
  unsigned short* vfr= (unsigned short*)(ws + 16777216);    //  8 MiB  V fragment layout (w-scaled, kv-perm)
  unsigned short* ao = (unsigned short*)(ws + 25165824);    //  8 MiB  [B,L,512]
  unsigned short* Wt = (unsigned short*)(ws + 33554432);    //  2 MiB  4x[512][512]
  unsigned short* vh = (unsigned short*)(ws + 35651584);    //  8 MiB  [B,H,L,64] row-major V
  unsigned short* wbf= (unsigned short*)(ws + 44040192);    // 16 KiB  [B,LKV] bf16 w (perm)

  transpose_w<<<dim3(16, 16, 4), 256, 0, stream>>>(Wq, Wk, Wv, Wo, wt, Wt, wbf);
  gemm_qkv<<<768, 256, 0, stream>>>(q, k, v, Wt, bq, bk, bv, qh, kh, vh);
  prep_v<<<dim3(32, 32), 256, 0, stream>>>(vh, wt, vfr);
  attn_fwd<<<512, 1024, 0, stream>>>(qh, kh, vfr, wbf, ao);
  gemm_out<<<256, 256, 0, stream>>>(ao, Wt + 3 * (size_t)DM * DM, bo, (float*)d_out);
}

// Round 18
// 88.697 us; speedup vs baseline: 9.3974x; 9.3974x over previous
//
#include <hip/hip_runtime.h>
#include <hip/hip_bf16.h>

#define LQ 2048
#define LKV 2048
#define DM 512
#define NH 8
#define DK 64

typedef __attribute__((ext_vector_type(8))) __bf16 bf16x8;
typedef __attribute__((ext_vector_type(4))) float f32x4;
typedef __attribute__((ext_vector_type(16))) float f32x16;

#define AS1 __attribute__((address_space(1)))
#define AS3 __attribute__((address_space(3)))

static __device__ __forceinline__ unsigned short f2bf(float x) {
  unsigned u = __float_as_uint(x);
  return (unsigned short)((u + 0x7fffu + ((u >> 16) & 1u)) >> 16);
}
static __device__ __forceinline__ float bf2f(unsigned short u) {
  return __uint_as_float(((unsigned)u) << 16);
}
static __device__ __forceinline__ bf16x8 cvt8(f32x4 a, f32x4 b) {
  bf16x8 r;
  r[0] = (__bf16)a[0]; r[1] = (__bf16)a[1]; r[2] = (__bf16)a[2]; r[3] = (__bf16)a[3];
  r[4] = (__bf16)b[0]; r[5] = (__bf16)b[1]; r[6] = (__bf16)b[2]; r[7] = (__bf16)b[3];
  return r;
}

// ---------------------------------------------------------------------------
// Transpose+convert W[512][512] f32 -> Wt bf16 (Wt[n][k] = W[k][n]).
// Blocks (z==0, y==0) additionally emit wbf[b][l] = bf16(w[l]) in the
// phi-permuted order (swap bits 2,3 of l&15) used by attn's w fragments.
// ---------------------------------------------------------------------------
__global__ __launch_bounds__(256) void transpose_w(
    const float* __restrict__ Wq, const float* __restrict__ Wk,
    const float* __restrict__ Wv, const float* __restrict__ Wo,
    const float* __restrict__ wts,
    unsigned short* __restrict__ WtAll, unsigned short* __restrict__ wbf)
{
  const float* W = blockIdx.z == 0 ? Wq : blockIdx.z == 1 ? Wk : blockIdx.z == 2 ? Wv : Wo;
  unsigned short* Wt = WtAll + (size_t)blockIdx.z * DM * DM;
  __shared__ float tile[32][33];
  const int t = threadIdx.x;
  if (blockIdx.z == 0 && blockIdx.y == 0) {
    int idx = blockIdx.x * 512 + t * 2;    // 16 blocks x 512 = 8192 = B*LKV
#pragma unroll
    for (int i = 0; i < 2; ++i) {
      int kv = idx + i;
      int r = kv & 15;
      int ph = (r & 3) | ((r & 4) << 1) | ((r & 8) >> 1);   // swap bits 2,3
      wbf[(kv & ~15) | ph] = f2bf(wts[kv]);
    }
  }
  const int tr = t >> 3;
  const int tc4 = (t & 7) * 4;
  const int k0 = blockIdx.x * 32, n0 = blockIdx.y * 32;
  float4 v = *(const float4*)(W + (size_t)(k0 + tr) * DM + n0 + tc4);
  tile[tr][tc4 + 0] = v.x; tile[tr][tc4 + 1] = v.y;
  tile[tr][tc4 + 2] = v.z; tile[tr][tc4 + 3] = v.w;
  __syncthreads();
  ushort4 o;
  o.x = f2bf(tile[tc4 + 0][tr]);
  o.y = f2bf(tile[tc4 + 1][tr]);
  o.z = f2bf(tile[tc4 + 2][tr]);
  o.w = f2bf(tile[tc4 + 3][tr]);
  *(ushort4*)(Wt + (size_t)(n0 + tr) * DM + k0 + tc4) = o;
}

// ---------------------------------------------------------------------------
// QKV projection GEMM with counted-vmcnt double-buffered pipeline.
// A f32 via global_load_lds (XOR-swizzled source); bf16 convert after LDS
// read. B via global_load_lds ((row>>1)&3 slot swizzle). XCD-bijective grid
// 768 = 3 modes x 64 m x 4 n, block 256. LDS 48 KB dbuf.
// Outputs ALL row-major head-major [B,H,L,64]: Q scaled by log2e/8, K, V.
// ---------------------------------------------------------------------------
__global__ __launch_bounds__(256) void gemm_qkv(
    const float* __restrict__ qin, const float* __restrict__ kin, const float* __restrict__ vin,
    const unsigned short* __restrict__ WtAll,
    const float* __restrict__ bq, const float* __restrict__ bk, const float* __restrict__ bv,
    unsigned short* __restrict__ qh, unsigned short* __restrict__ kh, unsigned short* __restrict__ vh)
{
  const int bid = blockIdx.x;
  const int x = bid & 7, j = bid >> 3;
  const int p = x + 8 * (j >> 2);
  const int nt = j & 3;
  const int mode = p >> 6, mtile = p & 63;

  const float* A = mode == 0 ? qin : (mode == 1 ? kin : vin);
  const unsigned short* Bt = WtAll + (size_t)mode * DM * DM;
  const float* bias = mode == 0 ? bq : (mode == 1 ? bk : bv);
  unsigned short* out = mode == 0 ? qh : (mode == 1 ? kh : vh);
  const float scale = (mode == 0) ? 0.18033688011112042f : 1.0f; // log2(e)/8

  // [buf2][As 16KB | Bs 8KB]
  __shared__ __align__(16) char sm[49152];

  const int tid = threadIdx.x;
  const int lane = tid & 63;
  const int w = tid >> 6;
  const int wr = w >> 1, wc = w & 1;
  const int l15 = lane & 15, g = lane >> 4;
  const int m0 = mtile * 128, n0 = nt * 128;

#define STAGEQ(buf, t)                                                                    \
  do {                                                                                    \
    int k0_ = (t) * 32;                                                                   \
    char* As_ = sm + (buf) * 24576;                                                       \
    char* Bs_ = As_ + 16384;                                                              \
    _Pragma("unroll")                                                                     \
    for (int i = 0; i < 4; ++i) {                                                         \
      int c = tid + i * 256;                                                              \
      int row = c >> 3, slot = c & 7;                                                     \
      const float* src = A + (size_t)(m0 + row) * DM + k0_ + ((slot ^ (row & 7)) << 2);   \
      __builtin_amdgcn_global_load_lds((const AS1 unsigned*)src,                          \
                                       (AS3 unsigned*)(As_ + c * 16), 16, 0, 0);          \
    }                                                                                     \
    _Pragma("unroll")                                                                     \
    for (int i = 0; i < 2; ++i) {                                                         \
      int c = tid + i * 256;                                                              \
      int row = c >> 2, slot = c & 3;                                                     \
      const unsigned short* src = Bt + (size_t)(n0 + row) * DM + k0_ + ((slot ^ ((row >> 1) & 3)) * 8); \
      __builtin_amdgcn_global_load_lds((const AS1 unsigned*)src,                          \
                                       (AS3 unsigned*)(Bs_ + c * 16), 16, 0, 0);          \
    }                                                                                     \
  } while (0)

  f32x4 acc[4][4] = {};
  STAGEQ(0, 0);
  int cur = 0;

  for (int t = 0; t < 16; ++t) {
    if (t < 15) {
      STAGEQ(cur ^ 1, t + 1);
      asm volatile("s_waitcnt vmcnt(6)" ::: "memory");   // stage t landed; 6 newest in flight
    } else {
      asm volatile("s_waitcnt vmcnt(0)" ::: "memory");
    }
    __builtin_amdgcn_s_barrier();      // A: buf cur complete

    const char* As_ = sm + cur * 24576;
    const char* Bs_ = As_ + 16384;

    __builtin_amdgcn_s_setprio(1);
    bf16x8 af[4], bfr[4];
#pragma unroll
    for (int mi = 0; mi < 4; ++mi) {
      int row = wr * 64 + mi * 16 + l15;
      f32x4 a0 = *(const f32x4*)(As_ + row * 128 + (((2 * g) ^ (row & 7)) << 4));
      f32x4 a1 = *(const f32x4*)(As_ + row * 128 + (((2 * g + 1) ^ (row & 7)) << 4));
      af[mi] = cvt8(a0, a1);
    }
#pragma unroll
    for (int ni = 0; ni < 4; ++ni) {
      int row = wc * 64 + ni * 16 + l15;
      bfr[ni] = *(const bf16x8*)(Bs_ + row * 64 + ((g ^ ((row >> 1) & 3)) * 16));
    }
#pragma unroll
    for (int mi = 0; mi < 4; ++mi)
#pragma unroll
      for (int ni = 0; ni < 4; ++ni)
        acc[mi][ni] = __builtin_amdgcn_mfma_f32_16x16x32_bf16(af[mi], bfr[ni], acc[mi][ni], 0, 0, 0);
    __builtin_amdgcn_s_setprio(0);

    asm volatile("s_waitcnt lgkmcnt(0)" ::: "memory");
    __builtin_amdgcn_s_barrier();      // B: reads of buf cur done; overwrite safe
    cur ^= 1;
  }
#undef STAGEQ

#pragma unroll
  for (int mi = 0; mi < 4; ++mi) {
#pragma unroll
    for (int ni = 0; ni < 4; ++ni) {
      int n = n0 + wc * 64 + ni * 16 + l15;
      float bs = bias[n];
      int h = n >> 6, d = n & 63;
#pragma unroll
      for (int r = 0; r < 4; ++r) {
        int m = m0 + wr * 64 + mi * 16 + g * 4 + r;
        int b = m >> 11, li = m & 2047;
        float val = (acc[mi][ni][r] + bs) * scale;
        out[(((size_t)(b * NH + h)) * LQ + li) * DK + d] = f2bf(val);
      }
    }
  }
}

// ---------------------------------------------------------------------------
// Output GEMM with counted-vmcnt double-buffered pipeline (vmcnt(4)) and
// XCD-bijective grid: all 4 n-tiles of one m-panel land on one XCD.
// grid 256 (1D), block 256. A bf16 @ Wo^T + bo -> f32.
// ---------------------------------------------------------------------------
__global__ __launch_bounds__(256) void gemm_out(
    const unsigned short* __restrict__ A, const unsigned short* __restrict__ Bt,
    const float* __restrict__ bias, float* __restrict__ out)
{
  // [buf2][Al 8KB | Bl 8KB]
  __shared__ __align__(16) char sm[32768];
  const int bid = blockIdx.x;
  const int x = bid & 7, j = bid >> 3;
  const int p = x + 8 * (j >> 2);        // m-tile 0..63 -> XCD p&7
  const int nt = j & 3;
  const int tid = threadIdx.x;
  const int lane = tid & 63;
  const int w = tid >> 6;
  const int wr = w >> 1, wc = w & 1;
  const int l15 = lane & 15, g = lane >> 4;
  const int m0 = p * 128, n0 = nt * 128;

#define STAGEO(buf, t)                                                                    \
  do {                                                                                    \
    int k0_ = (t) * 32;                                                                   \
    char* Al_ = sm + (buf) * 16384;                                                       \
    char* Bl_ = Al_ + 8192;                                                               \
    _Pragma("unroll")                                                                     \
    for (int i = 0; i < 2; ++i) {                                                         \
      int c = tid + i * 256;                                                              \
      int row = c >> 2, slot = c & 3;                                                     \
      int so = (slot ^ ((row >> 1) & 3)) * 8;                                             \
      __builtin_amdgcn_global_load_lds(                                                   \
          (const AS1 unsigned*)(A + (size_t)(m0 + row) * DM + k0_ + so),                  \
          (AS3 unsigned*)(Al_ + c * 16), 16, 0, 0);                                       \
      __builtin_amdgcn_global_load_lds(                                                   \
          (const AS1 unsigned*)(Bt + (size_t)(n0 + row) * DM + k0_ + so),                 \
          (AS3 unsigned*)(Bl_ + c * 16), 16, 0, 0);                                       \
    }                                                                                     \
  } while (0)

  f32x4 acc[4][4] = {};
  STAGEO(0, 0);
  int cur = 0;

  for (int t = 0; t < 16; ++t) {
    if (t < 15) {
      STAGEO(cur ^ 1, t + 1);
      asm volatile("s_waitcnt vmcnt(4)" ::: "memory");
    } else {
      asm volatile("s_waitcnt vmcnt(0)" ::: "memory");
    }
    __builtin_amdgcn_s_barrier();

    const char* Al_ = sm + cur * 16384;
    const char* Bl_ = Al_ + 8192;

    __builtin_amdgcn_s_setprio(1);
    bf16x8 af[4], bfr[4];
#pragma unroll
    for (int mi = 0; mi < 4; ++mi) {
      int row = wr * 64 + mi * 16 + l15;
      af[mi] = *(const bf16x8*)(Al_ + row * 64 + ((g ^ ((row >> 1) & 3)) * 16));
    }
#pragma unroll
    for (int ni = 0; ni < 4; ++ni) {
      int row = wc * 64 + ni * 16 + l15;
      bfr[ni] = *(const bf16x8*)(Bl_ + row * 64 + ((g ^ ((row >> 1) & 3)) * 16));
    }
#pragma unroll
    for (int mi = 0; mi < 4; ++mi)
#pragma unroll
      for (int ni = 0; ni < 4; ++ni)
        acc[mi][ni] = __builtin_amdgcn_mfma_f32_16x16x32_bf16(af[mi], bfr[ni], acc[mi][ni], 0, 0, 0);
    __builtin_amdgcn_s_setprio(0);

    asm volatile("s_waitcnt lgkmcnt(0)" ::: "memory");
    __builtin_amdgcn_s_barrier();
    cur ^= 1;
  }
#undef STAGEO

#pragma unroll
  for (int mi = 0; mi < 4; ++mi) {
#pragma unroll
    for (int ni = 0; ni < 4; ++ni) {
      int n = n0 + wc * 64 + ni * 16 + l15;
      float bs = bias[n];
#pragma unroll
      for (int r = 0; r < 4; ++r) {
        int m = m0 + wr * 64 + mi * 16 + g * 4 + r;
        out[(size_t)m * DM + n] = acc[mi][ni][r] + bs;
      }
    }
  }
}

// ---------------------------------------------------------------------------
// prep_v: V row-major -> w-folded B-fragment layout with kv-PERMUTED k-order
// (phi: swap bits 2<->3 of kv&15). grid (32, 32), block 256.
// ---------------------------------------------------------------------------
__global__ __launch_bounds__(256) void prep_v(
    const unsigned short* __restrict__ vh, const float* __restrict__ wts,
    unsigned short* __restrict__ vf)
{
  __shared__ __align__(16) unsigned short t[64 * 72];
  const int bh = blockIdx.y, l0 = blockIdx.x * 64;
  const int b = bh >> 3;
  const size_t base = (size_t)bh * LKV * DK;
  const int tid = threadIdx.x;

#pragma unroll
  for (int i = 0; i < 2; ++i) {
    int idx = tid + i * 256;
    int row = idx >> 3, seg = idx & 7;
    *(int4*)(&t[row * 72 + seg * 8]) =
        *(const int4*)(vh + base + (size_t)(l0 + row) * DK + seg * 8);
  }
  __syncthreads();
#pragma unroll
  for (int i = 0; i < 2; ++i) {
    int idx = tid + i * 256;
    int d = idx >> 3, seg = idx & 7;
    int kvg = l0 + seg * 8;
    float4 wa = *(const float4*)(wts + b * LKV + kvg);
    float4 wb4 = *(const float4*)(wts + b * LKV + kvg + 4);
    unsigned short r0 = f2bf(wa.x * bf2f(t[(seg * 8 + 0) * 72 + d]));
    unsigned short r1 = f2bf(wa.y * bf2f(t[(seg * 8 + 1) * 72 + d]));
    unsigned short r2 = f2bf(wa.z * bf2f(t[(seg * 8 + 2) * 72 + d]));
    unsigned short r3 = f2bf(wa.w * bf2f(t[(seg * 8 + 3) * 72 + d]));
    unsigned short r4 = f2bf(wb4.x * bf2f(t[(seg * 8 + 4) * 72 + d]));
    unsigned short r5 = f2bf(wb4.y * bf2f(t[(seg * 8 + 5) * 72 + d]));
    unsigned short r6 = f2bf(wb4.z * bf2f(t[(seg * 8 + 6) * 72 + d]));
    unsigned short r7 = f2bf(wb4.w * bf2f(t[(seg * 8 + 7) * 72 + d]));
    int T = kvg >> 4, s = (kvg >> 3) & 1, dh = d >> 5, dl = d & 31;
    size_t slot = (((size_t)bh * 128 + T) * 2 + dh) * 64;
    ushort4 lo4, hi4;
    lo4.x = r0; lo4.y = r1; lo4.z = r2; lo4.w = r3;
    hi4.x = r4; hi4.y = r5; hi4.z = r6; hi4.w = r7;
    *(ushort4*)(vf + (slot + dl) * 8 + 4 * s) = lo4;
    *(ushort4*)(vf + (slot + dl + 32) * 8 + 4 * s) = hi4;
  }
}

// ---------------------------------------------------------------------------
// Flash attention (r9/r14/r16 structure, best measured: 47.4-47.8 us).
// Counted-vmcnt 2-barrier pipeline. K gathered DIRECT from row-major kh via
// per-lane source addresses (fragment permutation at the global source; LDS
// dest/layout unchanged). V from phi-permuted vf (no lane exchange). w-row
// select via address-cndmask against a 64B LDS zero pad.
// 512-thread blocks = 8 waves = 4 wq x 2 kv-half. grid 512 = 32bh x 16qb.
// ---------------------------------------------------------------------------
__global__ __launch_bounds__(512, 4) void attn_fwd(
    const unsigned short* __restrict__ qh, const unsigned short* __restrict__ kh,
    const unsigned short* __restrict__ vf, const unsigned short* __restrict__ wbf,
    unsigned short* __restrict__ ao)
{
  const int bid = blockIdx.x;
  const int xcd = bid & 7, wi = bid >> 3;   // 512 blocks, 64 per XCD
  const int bh = xcd * 4 + (wi >> 4);       // 4 bh per XCD (L2 locality)
  const int qb = wi & 15;
  const int b = bh >> 3, h = bh & 7;
  const int tid = threadIdx.x, lane = tid & 63, w = tid >> 6;
  const int wq = w & 3, half = w >> 2;
  const int l31 = lane & 31, hi = lane >> 5;

  // [0,32768) K/V dbuf | [32768,36864) w bf16 | [36864,36928) zeros
  __shared__ __align__(16) char smem[36928];

  const size_t kv_bh = (size_t)bh * (LKV * DK);
  const unsigned short* khb = kh + kv_bh;
  const unsigned short* vfb = vf + kv_bh;

  const int q0 = qb * 128 + wq * 32;

#define STAGE(buf, t)                                                                     \
  do {                                                                                    \
    int tg_ = half * 32 + (t);                                                            \
    int kv_ = tg_ * 32 + (lane & 31);                                                     \
    const unsigned short* ks_ = khb + (size_t)kv_ * DK + wq * 16 + (lane >> 5) * 8;       \
    const unsigned short* vs_ = vfb + ((size_t)((tg_ * 2 + (wq >> 1)) * 2 + (wq & 1)) * 64 + lane) * 8; \
    char* kd_ = smem + (buf) * 16384 + half * 8192 + wq * 1024;                           \
    char* vd_ = smem + (buf) * 16384 + half * 8192 + 4096 + wq * 1024;                    \
    __builtin_amdgcn_global_load_lds((const AS1 unsigned*)ks_, (AS3 unsigned*)kd_, 16, 0, 0); \
    __builtin_amdgcn_global_load_lds((const AS1 unsigned*)vs_, (AS3 unsigned*)vd_, 16, 0, 0); \
  } while (0)

  // ---- prologue: w -> LDS, zero pad, first kv tile -> LDS, Q -> regs ----
  if (tid < 256)
    __builtin_amdgcn_global_load_lds((const AS1 unsigned*)(wbf + b * LKV + tid * 8),
                                     (AS3 unsigned*)(smem + 32768 + tid * 16), 16, 0, 0);
  if (tid < 16) *(int*)(smem + 36864 + tid * 4) = 0;
  STAGE(0, 0);

  bf16x8 qf[4];
  {
    const unsigned short* qp = qh + kv_bh + (size_t)(q0 + l31) * DK + hi * 8;
#pragma unroll
    for (int cq = 0; cq < 4; ++cq) qf[cq] = *(const bf16x8*)(qp + cq * 16);
  }
  __syncthreads();

  const char* wl = smem + 32768 + half * 2048 + hi * 16;
  const char* zpad = smem + 36864;
  f32x16 accO0 = {}, accO1 = {}, accL = {};
  int cur = 0;

#pragma unroll 2
  for (int t = 0; t < 32; ++t) {
    if (t < 31) {
      STAGE(cur ^ 1, t + 1);
      asm volatile("s_waitcnt vmcnt(2)" ::: "memory");   // buf cur landed; 2 newest in flight
    } else {
      asm volatile("s_waitcnt vmcnt(0)" ::: "memory");
    }
    __builtin_amdgcn_s_barrier();      // A: buf cur complete for all waves

    const char* Kb = smem + cur * 16384 + half * 8192;
    const char* Vb = Kb + 4096;

    __builtin_amdgcn_s_setprio(1);
    // ---- S^T = K.Q^T ----
    f32x16 s = {};
#pragma unroll
    for (int cq = 0; cq < 4; ++cq) {
      bf16x8 kfr = *(const bf16x8*)(Kb + cq * 1024 + lane * 16);
      s = __builtin_amdgcn_mfma_f32_32x32x16_bf16(kfr, qf[cq], s, 0, 0, 0);
    }

    // ---- u = exp2(S), pack bf16 pairs; C-layout == PV A-layout (perm'd) ----
    union { unsigned u[8]; bf16x8 v[2]; } P;
#pragma unroll
    for (int r2 = 0; r2 < 8; ++r2) {
      float lo = __builtin_amdgcn_exp2f(s[2 * r2]);
      float hv = __builtin_amdgcn_exp2f(s[2 * r2 + 1]);
      __bf16 bl = (__bf16)lo, bh2 = (__bf16)hv;
      unsigned short ul = __builtin_bit_cast(unsigned short, bl);
      unsigned short uh = __builtin_bit_cast(unsigned short, bh2);
      P.u[r2] = (unsigned)ul | ((unsigned)uh << 16);
    }

    // w-fragment base: real w row for lanes l31==0, zero pad otherwise
    const char* wsel = (l31 == 0) ? (wl + t * 64) : zpad;

    // ---- PV + denominator, pa = P.v[c] directly ----
#pragma unroll
    for (int c = 0; c < 2; ++c) {
      bf16x8 vb0 = *(const bf16x8*)(Vb + (c * 2 + 0) * 1024 + lane * 16);
      bf16x8 vb1 = *(const bf16x8*)(Vb + (c * 2 + 1) * 1024 + lane * 16);
      bf16x8 wb = *(const bf16x8*)(wsel + c * 32);

      accO0 = __builtin_amdgcn_mfma_f32_32x32x16_bf16(P.v[c], vb0, accO0, 0, 0, 0);
      accO1 = __builtin_amdgcn_mfma_f32_32x32x16_bf16(P.v[c], vb1, accO1, 0, 0, 0);
      accL  = __builtin_amdgcn_mfma_f32_32x32x16_bf16(P.v[c], wb,  accL,  0, 0, 0);
    }
    __builtin_amdgcn_s_setprio(0);

    asm volatile("s_waitcnt lgkmcnt(0)" ::: "memory");
    __builtin_amdgcn_s_barrier();      // B: all reads of buf cur done; next STAGE safe
    cur ^= 1;
  }
#undef STAGE

  // ---- combine kv-halves in LDS, normalize, store ----
  float* Ob = (float*)smem;                  // [4][32][68]
  float* Lb = (float*)(smem + 34816);        // [4][32]
  if (half == 1) {
#pragma unroll
    for (int r = 0; r < 16; ++r) {
      int qp_ = (r & 3) + 8 * (r >> 2) + 4 * hi;
      Ob[(wq * 32 + qp_) * 68 + l31] = accO0[r];
      Ob[(wq * 32 + qp_) * 68 + 32 + l31] = accO1[r];
    }
    if (l31 == 0) {
#pragma unroll
      for (int r = 0; r < 16; ++r) {
        int qp_ = (r & 3) + 8 * (r >> 2) + 4 * hi;
        Lb[wq * 32 + qp_] = accL[r];
      }
    }
  }
  __syncthreads();
  if (half == 0) {
#pragma unroll
    for (int r = 0; r < 16; ++r) {
      int qp_ = (r & 3) + 8 * (r >> 2) + 4 * hi;
      float L = __shfl(accL[r], lane & 32) + Lb[wq * 32 + qp_];
      float inv = 1.0f / L;
      float o0 = accO0[r] + Ob[(wq * 32 + qp_) * 68 + l31];
      float o1 = accO1[r] + Ob[(wq * 32 + qp_) * 68 + 32 + l31];
      size_t off = ((size_t)(b * LQ + q0 + qp_)) * DM + h * DK;
      ao[off + l31] = f2bf(o0 * inv);
      ao[off + 32 + l31] = f2bf(o1 * inv);
    }
  }
}

// ---------------------------------------------------------------------------
extern "C" void kernel_launch(void* const* d_in, const int* in_sizes, int n_in,
                              void* d_out, int out_size, void* d_ws, size_t ws_size,
                              hipStream_t stream)
{
  const float* q  = (const float*)d_in[0];
  const float* k  = (const float*)d_in[1];
  const float* v  = (const float*)d_in[2];
  const float* wt = (const float*)d_in[3];
  const float* Wq = (const float*)d_in[4];
  const float* bq = (const float*)d_in[5];
  const float* Wk = (const float*)d_in[6];
  const float* bk = (const float*)d_in[7];
  const float* Wv = (const float*)d_in[8];
  const float* bv = (const float*)d_in[9];
  const float* Wo = (const float*)d_in[10];
  const float* bo = (const float*)d_in[11];

  char* ws = (char*)d_ws;
  unsigned short* qh = (unsigned short*)(ws + 0);           //  8 MiB  [B,H,L,64] (scaled)
  unsigned short* kh = (unsigned short*)(ws + 8388608);     //  8 MiB  [B,H,L,64] row-major K
  unsigned short* vfr= (unsigned short*)(ws + 16777216);    //  8 MiB  V fragment layout (w-scaled, kv-perm)
  unsigned short* ao = (unsigned short*)(ws + 25165824);    //  8 MiB  [B,L,512]
  unsigned short* Wt = (unsigned short*)(ws + 33554432);    //  2 MiB  4x[512][512]
  unsigned short* vh = (unsigned short*)(ws + 35651584);    //  8 MiB  [B,H,L,64] row-major V
  unsigned short* wbf= (unsigned short*)(ws + 44040192);    // 16 KiB  [B,LKV] bf16 w (perm)

  transpose_w<<<dim3(16, 16, 4), 256, 0, stream>>>(Wq, Wk, Wv, Wo, wt, Wt, wbf);
  gemm_qkv<<<768, 256, 0, stream>>>(q, k, v, Wt, bq, bk, bv, qh, kh, vh);
  prep_v<<<dim3(32, 32), 256, 0, stream>>>(vh, wt, vfr);
  attn_fwd<<<512, 512, 0, stream>>>(qh, kh, vfr, wbf, ao);
  gemm_out<<<256, 256, 0, stream>>>(ao, Wt + 3 * (size_t)DM * DM, bo, (float*)d_out);
}